// Round 6
// baseline (133.220 us; speedup 1.0000x reference)
//
#include <hip/hip_runtime.h>

#define NROWS 8192
#define DIM   1024
#define EPSF  1e-8f

typedef __attribute__((ext_vector_type(4))) float f32x4;
typedef __attribute__((ext_vector_type(8))) short bf16x8;

typedef __attribute__((address_space(1))) void g_void;
typedef __attribute__((address_space(3))) void l_void;

__device__ __forceinline__ void async_copy16(void* lds, const void* g) {
  __builtin_amdgcn_global_load_lds((g_void*)const_cast<void*>(g), (l_void*)lds, 16, 0, 0);
}

__device__ __forceinline__ unsigned short f2bf(float f) {
  union { float f; unsigned u; } c; c.f = f;
  unsigned u = c.u;
  u += 0x7FFFu + ((u >> 16) & 1u);   // round-to-nearest-even
  return (unsigned short)(u >> 16);
}

__device__ __forceinline__ unsigned encf(float f) {
  const unsigned bits = __float_as_uint(f);
  return (bits & 0x80000000u) ? ~bits : (bits | 0x80000000u);
}

template<int N> __device__ __forceinline__ void vmwait() {
  if constexpr (N == 4)      asm volatile("s_waitcnt vmcnt(4)" ::: "memory");
  else                       asm volatile("s_waitcnt vmcnt(0)" ::: "memory");
}
__device__ __forceinline__ void barf() {
  __builtin_amdgcn_s_barrier();
  asm volatile("" ::: "memory");
}

// ---------------- Kernel A: row L2-normalize, cast to bf16, init maxenc ----------------
extern "C" __global__ __launch_bounds__(256)
void koleo_norm(const float* __restrict__ in, unsigned short* __restrict__ xb,
                unsigned* __restrict__ maxenc) {
  const int row = blockIdx.x;
  const int tid = threadIdx.x;
  const float4 v = reinterpret_cast<const float4*>(in + (size_t)row * DIM)[tid];
  float ss = v.x * v.x + v.y * v.y + v.z * v.z + v.w * v.w;
#pragma unroll
  for (int off = 32; off > 0; off >>= 1) ss += __shfl_down(ss, off);
  __shared__ float wsum[4];
  if ((tid & 63) == 0) wsum[tid >> 6] = ss;
  __syncthreads();
  const float total = wsum[0] + wsum[1] + wsum[2] + wsum[3];
  const float scale = 1.0f / (sqrtf(total) + EPSF);
  ushort4 o;
  o.x = f2bf(v.x * scale); o.y = f2bf(v.y * scale);
  o.z = f2bf(v.z * scale); o.w = f2bf(v.w * scale);
  reinterpret_cast<ushort4*>(xb + (size_t)row * DIM)[tid] = o;
  if (row < NROWS / 256) maxenc[row * 256 + tid] = 0u;  // enc(any real dot) > 0
}

// ---------------- Kernel B: upper-triangle Gram-max, 256x256 tile, BK=32, 2-phase ----------------
#define BM  256
#define BK  32
#define NT  (NROWS / BM)            // 32 tiles per dim
#define NBLK (NT * (NT + 1) / 2)    // 528 upper-triangle blocks
#define NKT (DIM / BK)              // 32 K-tiles

// stage one 16KB chunk = 256 rows x 64B (one operand, one K-tile). Linear:
// BK=32 gives 64B row stride -> frag reads are bank-uniform, no swizzle needed.
__device__ __forceinline__ void stage_chunk(char* dst, const char* gbase, int ktile, int tid) {
#pragma unroll
  for (int l = 0; l < 2; ++l) {
    const int o = l * 8192 + tid * 16;
    async_copy16(dst + o, gbase + (size_t)(o >> 6) * 2048 + ktile * 64 + (o & 63));
  }
}

#define MFMAQ(MH)                                                                     \
  {                                                                                   \
    _Pragma("unroll")                                                                 \
    for (int m = (MH) * 4; m < (MH) * 4 + 4; ++m)                                     \
      _Pragma("unroll")                                                               \
      for (int n = 0; n < 4; ++n)                                                     \
        acc[m][n] = __builtin_amdgcn_mfma_f32_16x16x32_bf16(                          \
            aF[m], bF[n], acc[m][n], 0, 0, 0);                                        \
  }

// Per K-tile t: read ALL frags from Lc, barrier (all reads queued), then stage
// tile t+2 into Lc (WAR-safe), MFMA half 0, vmwait<4> (t-1's stages = tile t+1
// data complete; t's 4 loads stay in flight), barrier, MFMA half 1.
template<bool SA, int V>
__device__ __forceinline__ void ktile(int t, char* Lc,
    const char* gA, const char* gB, int tid, int lane, int wr, int wc,
    bf16x8 (&aF)[8], bf16x8 (&bF)[4], f32x4 (&acc)[8][4]) {
  const int lr = lane & 15, lg = lane >> 4;
#pragma unroll
  for (int m = 0; m < 8; ++m)
    aF[m] = *(const bf16x8*)(Lc + (wr * 128 + m * 16 + lr) * 64 + lg * 16);
#pragma unroll
  for (int n = 0; n < 4; ++n)
    bF[n] = *(const bf16x8*)(Lc + 16384 + (wc * 64 + n * 16 + lr) * 64 + lg * 16);
  barf();                                   // all waves' reads queued before stages
  if constexpr (SA) {
    stage_chunk(Lc,         gA, t + 2, tid);
    stage_chunk(Lc + 16384, gB, t + 2, tid);
  }
  __builtin_amdgcn_s_setprio(1); MFMAQ(0); __builtin_amdgcn_s_setprio(0);
  vmwait<V>();                              // tile t+1 data complete
  barf();
  __builtin_amdgcn_s_setprio(1); MFMAQ(1); __builtin_amdgcn_s_setprio(0);
}

extern "C" __global__ __launch_bounds__(512)
void koleo_grammax(const unsigned short* __restrict__ xb, unsigned* __restrict__ maxenc) {
  __shared__ char lds[65536];   // 2 dbuf x (A 16KB + B 16KB); 2 blocks/CU

  const int tid  = threadIdx.x;
  const int lane = tid & 63;
  const int wid  = tid >> 6;
  const int wr   = wid >> 2;     // 0..1: rows wr*128..+127
  const int wc   = wid & 3;      // 0..3: cols wc*64..+63
  const int lr   = lane & 15;
  const int lg   = lane >> 4;

  // XCD-aware bijective swizzle (528 % 8 == 0)
  const int bid = (blockIdx.x % 8) * (NBLK / 8) + blockIdx.x / 8;
  // upper-triangle decode (ti <= tj)
  int ti = (int)((2.0f * NT + 1.0f -
                  sqrtf((float)((2 * NT + 1) * (2 * NT + 1) - 8 * bid))) * 0.5f);
  while ((ti + 1) * NT - ((ti + 1) * ti) / 2 <= bid) ++ti;
  while (ti * NT - (ti * (ti - 1)) / 2 > bid) --ti;
  const int tj = ti + (bid - (ti * NT - (ti * (ti - 1)) / 2));

  const int rowBase = ti * BM;
  const int colBase = tj * BM;
  const bool diag = (ti == tj);

  const char* xbb = (const char*)xb;
  const char* gA = xbb + (size_t)rowBase * 2048;
  const char* gB = xbb + (size_t)colBase * 2048;
  char* L0 = lds;
  char* L1 = lds + 32768;

  f32x4  acc[8][4] = {};
  bf16x8 aF[8];
  bf16x8 bF[4];

  // prologue: tiles 0 -> L0, 1 -> L1 (issue order defines vmcnt arithmetic)
  stage_chunk(L0,         gA, 0, tid);
  stage_chunk(L0 + 16384, gB, 0, tid);
  stage_chunk(L1,         gA, 1, tid);
  stage_chunk(L1 + 16384, gB, 1, tid);
  vmwait<4>();   // tile 0 complete; tile 1's 4 loads in flight
  barf();

#pragma unroll 1
  for (int t2 = 0; t2 < 30; t2 += 2) {
    ktile<true, 4>(t2,     L0, gA, gB, tid, lane, wr, wc, aF, bF, acc);
    ktile<true, 4>(t2 + 1, L1, gA, gB, tid, lane, wr, wc, aF, bF, acc);
  }
  ktile<false, 0>(30, L0, gA, gB, tid, lane, wr, wc, aF, bF, acc);
  ktile<false, 0>(31, L1, gA, gB, tid, lane, wr, wc, aF, bF, acc);

  // ---- epilogue: per-row / per-col max with diagonal mask ----
  __syncthreads();
  unsigned* smaxr = (unsigned*)lds;           // [256]
  unsigned* smaxc = (unsigned*)(lds + 1024);  // [256]
  if (tid < 256) { smaxr[tid] = 0u; smaxc[tid] = 0u; }
  __syncthreads();

#pragma unroll
  for (int m = 0; m < 8; ++m) {
#pragma unroll
    for (int rr = 0; rr < 4; ++rr) {
      const int lrow = wr * 128 + m * 16 + lg * 4 + rr;  // C/D: row=(lane>>4)*4+reg
      const int grow = rowBase + lrow;
      float mx = -2.0f;
#pragma unroll
      for (int n = 0; n < 4; ++n) {
        float v = acc[m][n][rr];
        const int gcol = colBase + wc * 64 + n * 16 + lr;  // C/D: col=lane&15
        if (grow == gcol) v = -2.0f;                        // mask self-similarity
        mx = fmaxf(mx, v);
      }
#pragma unroll
      for (int off = 1; off < 16; off <<= 1) mx = fmaxf(mx, __shfl_xor(mx, off));
      if (lr == 0) atomicMax(&smaxr[lrow], encf(mx));
    }
  }
  if (!diag) {  // symmetric fold: col j's max over this block's rows
#pragma unroll
    for (int n = 0; n < 4; ++n) {
      const int lcol = wc * 64 + n * 16 + lr;
      float mx = -2.0f;
#pragma unroll
      for (int m = 0; m < 8; ++m)
#pragma unroll
        for (int rr = 0; rr < 4; ++rr) mx = fmaxf(mx, acc[m][n][rr]);
      mx = fmaxf(mx, __shfl_xor(mx, 16));
      mx = fmaxf(mx, __shfl_xor(mx, 32));
      if (lg == 0) atomicMax(&smaxc[lcol], encf(mx));
    }
  }
  __syncthreads();
  if (tid < 256) {
    atomicMax(&maxenc[rowBase + tid], smaxr[tid]);
    if (!diag) atomicMax(&maxenc[colBase + tid], smaxc[tid]);
  }
}

// ---------------- Kernel C: loss reduction ----------------
extern "C" __global__ __launch_bounds__(256)
void koleo_loss(const unsigned* __restrict__ maxenc, float* __restrict__ out) {
  const int tid = threadIdx.x;
  float sum = 0.0f;
  for (int i = tid; i < NROWS; i += 256) {
    const unsigned u    = maxenc[i];
    const unsigned bits = (u & 0x80000000u) ? (u & 0x7FFFFFFFu) : ~u;
    const float m = __uint_as_float(bits);
    const float d = sqrtf(fmaxf(2.0f - 2.0f * m, 0.0f)) + EPSF;  // ||x_i - x_nn|| + eps
    sum += logf(d + EPSF);
  }
#pragma unroll
  for (int off = 32; off > 0; off >>= 1) sum += __shfl_down(sum, off);
  __shared__ float wsum[4];
  if ((tid & 63) == 0) wsum[tid >> 6] = sum;
  __syncthreads();
  if (tid == 0) out[0] = -(wsum[0] + wsum[1] + wsum[2] + wsum[3]) / (float)NROWS;
}

extern "C" void kernel_launch(void* const* d_in, const int* in_sizes, int n_in,
                              void* d_out, int out_size, void* d_ws, size_t ws_size,
                              hipStream_t stream) {
  const float* in = (const float*)d_in[0];
  unsigned short* xb = (unsigned short*)d_ws;                                  // 16 MB bf16 x
  unsigned* maxenc   = (unsigned*)((char*)d_ws + (size_t)NROWS * DIM * 2);     // 32 KB
  float* out = (float*)d_out;

  hipLaunchKernelGGL(koleo_norm,    dim3(NROWS), dim3(256), 0, stream, in, xb, maxenc);
  hipLaunchKernelGGL(koleo_grammax, dim3(NBLK),  dim3(512), 0, stream, xb, maxenc);
  hipLaunchKernelGGL(koleo_loss,    dim3(1),     dim3(256), 0, stream, maxenc, out);
}

// Round 7
// 129.238 us; speedup vs baseline: 1.0308x; 1.0308x over previous
//
#include <hip/hip_runtime.h>

#define NROWS 8192
#define DIM   1024
#define EPSF  1e-8f

typedef __attribute__((ext_vector_type(4))) float f32x4;
typedef __attribute__((ext_vector_type(8))) short bf16x8;

typedef __attribute__((address_space(1))) void g_void;
typedef __attribute__((address_space(3))) void l_void;

__device__ __forceinline__ void async_copy16(void* lds, const void* g) {
  __builtin_amdgcn_global_load_lds((g_void*)const_cast<void*>(g), (l_void*)lds, 16, 0, 0);
}

__device__ __forceinline__ unsigned short f2bf(float f) {
  union { float f; unsigned u; } c; c.f = f;
  unsigned u = c.u;
  u += 0x7FFFu + ((u >> 16) & 1u);   // round-to-nearest-even
  return (unsigned short)(u >> 16);
}

__device__ __forceinline__ unsigned encf(float f) {
  const unsigned bits = __float_as_uint(f);
  return (bits & 0x80000000u) ? ~bits : (bits | 0x80000000u);
}

template<int N> __device__ __forceinline__ void vmwait() {
  if constexpr (N == 8)      asm volatile("s_waitcnt vmcnt(8)" ::: "memory");
  else if constexpr (N == 4) asm volatile("s_waitcnt vmcnt(4)" ::: "memory");
  else                       asm volatile("s_waitcnt vmcnt(0)" ::: "memory");
}
__device__ __forceinline__ void barf() {
  __builtin_amdgcn_s_barrier();
  asm volatile("" ::: "memory");
}

// ---------------- Kernel A: row L2-normalize, cast to bf16, init maxenc ----------------
extern "C" __global__ __launch_bounds__(256)
void koleo_norm(const float* __restrict__ in, unsigned short* __restrict__ xb,
                unsigned* __restrict__ maxenc) {
  const int row = blockIdx.x;
  const int tid = threadIdx.x;
  const float4 v = reinterpret_cast<const float4*>(in + (size_t)row * DIM)[tid];
  float ss = v.x * v.x + v.y * v.y + v.z * v.z + v.w * v.w;
#pragma unroll
  for (int off = 32; off > 0; off >>= 1) ss += __shfl_down(ss, off);
  __shared__ float wsum[4];
  if ((tid & 63) == 0) wsum[tid >> 6] = ss;
  __syncthreads();
  const float total = wsum[0] + wsum[1] + wsum[2] + wsum[3];
  const float scale = 1.0f / (sqrtf(total) + EPSF);
  ushort4 o;
  o.x = f2bf(v.x * scale); o.y = f2bf(v.y * scale);
  o.z = f2bf(v.z * scale); o.w = f2bf(v.w * scale);
  reinterpret_cast<ushort4*>(xb + (size_t)row * DIM)[tid] = o;
  if (row < NROWS / 256) maxenc[row * 256 + tid] = 0u;  // enc(any real dot) > 0
}

// ---------------- Kernel B: upper-triangle Gram-max, 256x256, BK=64, 2-phase ----------------
#define BM  256
#define BK  64
#define NT  (NROWS / BM)            // 32 tiles per dim
#define NBLK (NT * (NT + 1) / 2)    // 528 upper-triangle blocks
#define NKT (DIM / BK)              // 16 K-tiles

// stage one 16KB chunk (128 rows x 128B), XOR-swizzled source so LDS holds
// LDS[o] = logical[o ^ ((row&7)<<4)] with linear gload_lds destination
// (R5-proven: 0 bank conflicts on the paired reads)
__device__ __forceinline__ void stage_chunk(char* dst, const char* gbase, int ktile, int tid) {
#pragma unroll
  for (int l = 0; l < 2; ++l) {
    const int o  = l * 8192 + tid * 16;
    const int so = o ^ (((o >> 7) & 7) << 4);
    async_copy16(dst + o, gbase + (size_t)(so >> 7) * 2048 + ktile * 128 + (so & 127));
  }
}

#define READ_AB(KK)                                                                   \
  {                                                                                   \
    _Pragma("unroll")                                                                 \
    for (int m = 0; m < 8; ++m)                                                       \
      aF[m] = *(const bf16x8*)(Lc +                                                   \
          (((wr * 128 + m * 16 + lr) * 128 + (KK) * 64 + lg * 16) ^ xr));             \
    _Pragma("unroll")                                                                 \
    for (int n = 0; n < 4; ++n)                                                       \
      bF[n] = *(const bf16x8*)(Lc + 32768 +                                           \
          (((wc * 64 + n * 16 + lr) * 128 + (KK) * 64 + lg * 16) ^ xr));              \
  }

#define MFMAK()                                                                       \
  {                                                                                   \
    _Pragma("unroll")                                                                 \
    for (int m = 0; m < 8; ++m)                                                       \
      _Pragma("unroll")                                                               \
      for (int n = 0; n < 4; ++n)                                                     \
        acc[m][n] = __builtin_amdgcn_mfma_f32_16x16x32_bf16(                          \
            aF[m], bF[n], acc[m][n], 0, 0, 0);                                        \
  }

// Per K-tile t (buffer Lc): P0 {read kk0, MFMA}; P1 {read kk1, BAR (all tile-t
// reads precede stages), stage tile t+2 -> Lc (8 loads), vmwait<8> (= t+1's
// stages complete, t+2's 8 loads stay in flight), BAR (cross-wave fence), MFMA}.
template<bool ST, int V>
__device__ __forceinline__ void ktile(int t, char* Lc,
    const char* gA0, const char* gA1, const char* gB0, const char* gB1,
    int tid, int lane, int wr, int wc,
    bf16x8 (&aF)[8], bf16x8 (&bF)[4], f32x4 (&acc)[8][4]) {
  const int lr = lane & 15, lg = lane >> 4;
  const int xr = (lane & 7) << 4;
  // ---- P0 ----
  READ_AB(0);
  __builtin_amdgcn_s_setprio(1); MFMAK(); __builtin_amdgcn_s_setprio(0);
  // ---- P1 ----
  READ_AB(1);
  barf();                                   // all waves' tile-t reads queued
  if constexpr (ST) {
    stage_chunk(Lc,         gA0, t + 2, tid);
    stage_chunk(Lc + 16384, gA1, t + 2, tid);
    stage_chunk(Lc + 32768, gB0, t + 2, tid);
    stage_chunk(Lc + 49152, gB1, t + 2, tid);
  }
  if constexpr (V >= 0) vmwait<V>();        // tile t+1 data complete
  barf();                                   // fence before next tile's reads
  __builtin_amdgcn_s_setprio(1); MFMAK(); __builtin_amdgcn_s_setprio(0);
}

extern "C" __global__ __launch_bounds__(512)
void koleo_grammax(const unsigned short* __restrict__ xb, unsigned* __restrict__ maxenc) {
  __shared__ char lds[131072];   // 2 dbuf x (A 32KB + B 32KB)

  const int tid  = threadIdx.x;
  const int lane = tid & 63;
  const int wid  = tid >> 6;
  const int wr   = wid >> 2;     // 0..1: rows wr*128..+127
  const int wc   = wid & 3;      // 0..3: cols wc*64..+63
  const int lr   = lane & 15;
  const int lg   = lane >> 4;

  // XCD-aware bijective swizzle (528 % 8 == 0)
  const int bid = (blockIdx.x % 8) * (NBLK / 8) + blockIdx.x / 8;
  // upper-triangle decode (ti <= tj)
  int ti = (int)((2.0f * NT + 1.0f -
                  sqrtf((float)((2 * NT + 1) * (2 * NT + 1) - 8 * bid))) * 0.5f);
  while ((ti + 1) * NT - ((ti + 1) * ti) / 2 <= bid) ++ti;
  while (ti * NT - (ti * (ti - 1)) / 2 > bid) --ti;
  const int tj = ti + (bid - (ti * NT - (ti * (ti - 1)) / 2));

  const int rowBase = ti * BM;
  const int colBase = tj * BM;
  const bool diag = (ti == tj);

  const char* xbb = (const char*)xb;
  const char* gA0 = xbb + (size_t)rowBase * 2048;
  const char* gA1 = xbb + (size_t)(rowBase + 128) * 2048;
  const char* gB0 = xbb + (size_t)colBase * 2048;
  const char* gB1 = xbb + (size_t)(colBase + 128) * 2048;
  char* L0 = lds;
  char* L1 = lds + 65536;

  f32x4  acc[8][4] = {};
  bf16x8 aF[8];
  bf16x8 bF[4];

  // prologue: tile 0 -> L0 (8 loads), tile 1 -> L1 (8 loads)
  stage_chunk(L0,         gA0, 0, tid);
  stage_chunk(L0 + 16384, gA1, 0, tid);
  stage_chunk(L0 + 32768, gB0, 0, tid);
  stage_chunk(L0 + 49152, gB1, 0, tid);
  stage_chunk(L1,         gA0, 1, tid);
  stage_chunk(L1 + 16384, gA1, 1, tid);
  stage_chunk(L1 + 32768, gB0, 1, tid);
  stage_chunk(L1 + 49152, gB1, 1, tid);
  vmwait<8>();   // tile 0 complete; tile 1's 8 loads in flight
  barf();

#pragma unroll 1
  for (int t2 = 0; t2 < 14; t2 += 2) {
    ktile<true, 8>(t2,     L0, gA0, gA1, gB0, gB1, tid, lane, wr, wc, aF, bF, acc);
    ktile<true, 8>(t2 + 1, L1, gA0, gA1, gB0, gB1, tid, lane, wr, wc, aF, bF, acc);
  }
  ktile<false, 0>(14, L0, gA0, gA1, gB0, gB1, tid, lane, wr, wc, aF, bF, acc);
  ktile<false, -1>(15, L1, gA0, gA1, gB0, gB1, tid, lane, wr, wc, aF, bF, acc);

  // ---- epilogue: per-row / per-col max with diagonal mask ----
  __syncthreads();
  unsigned* smaxr = (unsigned*)lds;           // [256]
  unsigned* smaxc = (unsigned*)(lds + 1024);  // [256]
  if (tid < 256) { smaxr[tid] = 0u; smaxc[tid] = 0u; }
  __syncthreads();

#pragma unroll
  for (int m = 0; m < 8; ++m) {
#pragma unroll
    for (int rr = 0; rr < 4; ++rr) {
      const int lrow = wr * 128 + m * 16 + lg * 4 + rr;  // C/D: row=(lane>>4)*4+reg
      const int grow = rowBase + lrow;
      float mx = -2.0f;
#pragma unroll
      for (int n = 0; n < 4; ++n) {
        float v = acc[m][n][rr];
        const int gcol = colBase + wc * 64 + n * 16 + lr;  // C/D: col=lane&15
        if (grow == gcol) v = -2.0f;                        // mask self-similarity
        mx = fmaxf(mx, v);
      }
#pragma unroll
      for (int off = 1; off < 16; off <<= 1) mx = fmaxf(mx, __shfl_xor(mx, off));
      if (lr == 0) atomicMax(&smaxr[lrow], encf(mx));
    }
  }
  if (!diag) {  // symmetric fold: col j's max over this block's rows
#pragma unroll
    for (int n = 0; n < 4; ++n) {
      const int lcol = wc * 64 + n * 16 + lr;
      float mx = -2.0f;
#pragma unroll
      for (int m = 0; m < 8; ++m)
#pragma unroll
        for (int rr = 0; rr < 4; ++rr) mx = fmaxf(mx, acc[m][n][rr]);
      mx = fmaxf(mx, __shfl_xor(mx, 16));
      mx = fmaxf(mx, __shfl_xor(mx, 32));
      if (lg == 0) atomicMax(&smaxc[lcol], encf(mx));
    }
  }
  __syncthreads();
  if (tid < 256) {
    atomicMax(&maxenc[rowBase + tid], smaxr[tid]);
    if (!diag) atomicMax(&maxenc[colBase + tid], smaxc[tid]);
  }
}

// ---------------- Kernel C: loss reduction ----------------
extern "C" __global__ __launch_bounds__(256)
void koleo_loss(const unsigned* __restrict__ maxenc, float* __restrict__ out) {
  const int tid = threadIdx.x;
  float sum = 0.0f;
  for (int i = tid; i < NROWS; i += 256) {
    const unsigned u    = maxenc[i];
    const unsigned bits = (u & 0x80000000u) ? (u & 0x7FFFFFFFu) : ~u;
    const float m = __uint_as_float(bits);
    const float d = sqrtf(fmaxf(2.0f - 2.0f * m, 0.0f)) + EPSF;  // ||x_i - x_nn|| + eps
    sum += logf(d + EPSF);
  }
#pragma unroll
  for (int off = 32; off > 0; off >>= 1) sum += __shfl_down(sum, off);
  __shared__ float wsum[4];
  if ((tid & 63) == 0) wsum[tid >> 6] = sum;
  __syncthreads();
  if (tid == 0) out[0] = -(wsum[0] + wsum[1] + wsum[2] + wsum[3]) / (float)NROWS;
}

extern "C" void kernel_launch(void* const* d_in, const int* in_sizes, int n_in,
                              void* d_out, int out_size, void* d_ws, size_t ws_size,
                              hipStream_t stream) {
  const float* in = (const float*)d_in[0];
  unsigned short* xb = (unsigned short*)d_ws;                                  // 16 MB bf16 x
  unsigned* maxenc   = (unsigned*)((char*)d_ws + (size_t)NROWS * DIM * 2);     // 32 KB
  float* out = (float*)d_out;

  hipLaunchKernelGGL(koleo_norm,    dim3(NROWS), dim3(256), 0, stream, in, xb, maxenc);
  hipLaunchKernelGGL(koleo_grammax, dim3(NBLK),  dim3(512), 0, stream, xb, maxenc);
  hipLaunchKernelGGL(koleo_loss,    dim3(1),     dim3(256), 0, stream, maxenc, out);
}

// Round 8
// 127.989 us; speedup vs baseline: 1.0409x; 1.0098x over previous
//
#include <hip/hip_runtime.h>

#define NROWS 8192
#define DIM   1024
#define EPSF  1e-8f

typedef __attribute__((ext_vector_type(4))) float f32x4;
typedef __attribute__((ext_vector_type(8))) short bf16x8;

typedef __attribute__((address_space(1))) void g_void;
typedef __attribute__((address_space(3))) void l_void;

__device__ __forceinline__ void async_copy16(void* lds, const void* g) {
  __builtin_amdgcn_global_load_lds((g_void*)const_cast<void*>(g), (l_void*)lds, 16, 0, 0);
}

__device__ __forceinline__ unsigned short f2bf(float f) {
  union { float f; unsigned u; } c; c.f = f;
  unsigned u = c.u;
  u += 0x7FFFu + ((u >> 16) & 1u);   // round-to-nearest-even
  return (unsigned short)(u >> 16);
}

__device__ __forceinline__ unsigned encf(float f) {
  const unsigned bits = __float_as_uint(f);
  return (bits & 0x80000000u) ? ~bits : (bits | 0x80000000u);
}

template<int N> __device__ __forceinline__ void vmwait() {
  if constexpr (N == 4)      asm volatile("s_waitcnt vmcnt(4)" ::: "memory");
  else                       asm volatile("s_waitcnt vmcnt(0)" ::: "memory");
}
__device__ __forceinline__ void barf() {
  __builtin_amdgcn_s_barrier();
  asm volatile("" ::: "memory");
}

// ---------------- Kernel A: row L2-normalize, cast to bf16, init maxenc ----------------
extern "C" __global__ __launch_bounds__(256)
void koleo_norm(const float* __restrict__ in, unsigned short* __restrict__ xb,
                unsigned* __restrict__ maxenc) {
  const int row = blockIdx.x;
  const int tid = threadIdx.x;
  const float4 v = reinterpret_cast<const float4*>(in + (size_t)row * DIM)[tid];
  float ss = v.x * v.x + v.y * v.y + v.z * v.z + v.w * v.w;
#pragma unroll
  for (int off = 32; off > 0; off >>= 1) ss += __shfl_down(ss, off);
  __shared__ float wsum[4];
  if ((tid & 63) == 0) wsum[tid >> 6] = ss;
  __syncthreads();
  const float total = wsum[0] + wsum[1] + wsum[2] + wsum[3];
  const float scale = 1.0f / (sqrtf(total) + EPSF);
  ushort4 o;
  o.x = f2bf(v.x * scale); o.y = f2bf(v.y * scale);
  o.z = f2bf(v.z * scale); o.w = f2bf(v.w * scale);
  reinterpret_cast<ushort4*>(xb + (size_t)row * DIM)[tid] = o;
  if (row < NROWS / 256) maxenc[row * 256 + tid] = 0u;  // enc(any real dot) > 0
}

// -------- Kernel B: upper-triangle Gram-max, 256x256, BK=64, 4-phase/K-tile pipeline --------
#define BM  256
#define BK  64
#define NT  (NROWS / BM)            // 32 tiles per dim
#define NBLK (NT * (NT + 1) / 2)    // 528 upper-triangle blocks
#define NKT (DIM / BK)              // 16 K-tiles

// LDS buffer layout (64 KB/buffer): [A-sub0 | A-sub1 | B-sub0 | B-sub1], 16 KB each.
// A-sub s holds rows r with ((r>>6)&1)==s  (read only in phases {s?2,3:0,1})
// B-sub s holds cols c with ((c>>5)&1)==s  (read only in phases {s?1,3:0,2})
// Each sub staged as 128 chunk-rows x 128B, XOR-swizzled source (R5-proven 0-conflict):
// LDS[o] = logical[row=o>>7][byte=(o&127)^(((o>>7)&7)<<4)]

__device__ __forceinline__ void stage_subA(char* dst, const char* gbase, int sub, int kt, int tid) {
#pragma unroll
  for (int l = 0; l < 2; ++l) {
    const int o  = l * 8192 + tid * 16;
    const int so = o ^ (((o >> 7) & 7) << 4);
    const int i  = so >> 7;                       // chunk row 0..127
    const int r  = sub * 64 + (i & 63) + ((i & 64) << 1);   // global row in tile
    async_copy16(dst + o, gbase + (size_t)r * 2048 + kt * 128 + (so & 127));
  }
}
__device__ __forceinline__ void stage_subB(char* dst, const char* gbase, int sub, int kt, int tid) {
#pragma unroll
  for (int l = 0; l < 2; ++l) {
    const int o  = l * 8192 + tid * 16;
    const int so = o ^ (((o >> 7) & 7) << 4);
    const int j  = so >> 7;
    const int c  = sub * 32 + (j & 31) + ((j >> 5) << 6);   // global col in tile
    async_copy16(dst + o, gbase + (size_t)c * 2048 + kt * 128 + (so & 127));
  }
}

// chunk-row for A read: i = (mm*16+lr) + wr*64 ; for B: j = (nn*16+lr) + wc*32
#define READ_A(MH)                                                                    \
  {                                                                                   \
    _Pragma("unroll")                                                                 \
    for (int mm = 0; mm < 4; ++mm)                                                    \
      _Pragma("unroll")                                                               \
      for (int kk = 0; kk < 2; ++kk)                                                  \
        aF[mm][kk] = *(const bf16x8*)(Lc + (MH) * 16384 +                             \
            ((((mm * 16 + lr) + wr * 64) * 128 + kk * 64 + lg * 16) ^ xr));           \
  }
#define READ_B(NH)                                                                    \
  {                                                                                   \
    _Pragma("unroll")                                                                 \
    for (int nn = 0; nn < 2; ++nn)                                                    \
      _Pragma("unroll")                                                               \
      for (int kk = 0; kk < 2; ++kk)                                                  \
        bF[nn][kk] = *(const bf16x8*)(Lc + 32768 + (NH) * 16384 +                     \
            ((((nn * 16 + lr) + wc * 32) * 128 + kk * 64 + lg * 16) ^ xr));           \
  }
#define MFMAQ(MH, NH)                                                                 \
  {                                                                                   \
    _Pragma("unroll")                                                                 \
    for (int kk = 0; kk < 2; ++kk)                                                    \
      _Pragma("unroll")                                                               \
      for (int mm = 0; mm < 4; ++mm)                                                  \
        _Pragma("unroll")                                                             \
        for (int nn = 0; nn < 2; ++nn)                                                \
          acc[(MH)*4 + mm][(NH)*2 + nn] = __builtin_amdgcn_mfma_f32_16x16x32_bf16(    \
              aF[mm][kk], bF[nn][kk], acc[(MH)*4 + mm][(NH)*2 + nn], 0, 0, 0);        \
  }

// Tile t reads buf Lc. Stage schedule (1 sub/phase, WAR-safe by last-read phase):
//   p0: A-sub1(t+1)->Ln   p1: B-sub1(t+1)->Ln   p2: A-sub0(t+2)->Lc   p3: B-sub0(t+2)->Lc
// Single counted vmcnt(4) at p3 forces tile-(t+1) data complete, keeps the
// 4 newest loads (tile t+2's A-sub0,B-sub0) in flight. Never drains to 0 mid-loop.
template<bool S01, bool S23, int VB>
__device__ __forceinline__ void ktile(int t, char* Lc, char* Ln,
    const char* gA, const char* gB, int tid, int lane, int wr, int wc,
    bf16x8 (&aF)[4][2], bf16x8 (&bF)[2][2], f32x4 (&acc)[8][4]) {
  const int lr = lane & 15, lg = lane >> 4;
  const int xr = (lane & 7) << 4;
  // ---- p0: quadrant (0,0) ----
  READ_A(0); READ_B(0);
  if constexpr (S01) stage_subA(Ln + 16384, gA, 1, t + 1, tid);
  barf();
  __builtin_amdgcn_s_setprio(1); MFMAQ(0, 0); __builtin_amdgcn_s_setprio(0);
  barf();
  // ---- p1: quadrant (0,1), aF reused ----
  READ_B(1);
  if constexpr (S01) stage_subB(Ln + 49152, gB, 1, t + 1, tid);
  barf();
  __builtin_amdgcn_s_setprio(1); MFMAQ(0, 1); __builtin_amdgcn_s_setprio(0);
  barf();
  // ---- p2: quadrant (1,0) ----
  READ_A(1); READ_B(0);
  if constexpr (S23) stage_subA(Lc, gA, 0, t + 2, tid);
  barf();
  __builtin_amdgcn_s_setprio(1); MFMAQ(1, 0); __builtin_amdgcn_s_setprio(0);
  barf();
  // ---- p3: quadrant (1,1), aF reused; the one counted wait per K-tile ----
  READ_B(1);
  if constexpr (S23) stage_subB(Lc + 32768, gB, 0, t + 2, tid);
  if constexpr (VB >= 0) vmwait<VB>();
  barf();
  __builtin_amdgcn_s_setprio(1); MFMAQ(1, 1); __builtin_amdgcn_s_setprio(0);
  barf();
}

extern "C" __global__ __launch_bounds__(512)
void koleo_grammax(const unsigned short* __restrict__ xb, unsigned* __restrict__ maxenc) {
  __shared__ char lds[131072];   // 2 dbuf x 64KB

  const int tid  = threadIdx.x;
  const int lane = tid & 63;
  const int wid  = tid >> 6;
  const int wr   = wid >> 2;     // 0..1: rows wr*128..+127
  const int wc   = wid & 3;      // 0..3: cols wc*64..+63
  const int lr   = lane & 15;
  const int lg   = lane >> 4;

  // XCD-aware bijective swizzle (528 % 8 == 0)
  const int bid = (blockIdx.x % 8) * (NBLK / 8) + blockIdx.x / 8;
  // upper-triangle decode (ti <= tj)
  int ti = (int)((2.0f * NT + 1.0f -
                  sqrtf((float)((2 * NT + 1) * (2 * NT + 1) - 8 * bid))) * 0.5f);
  while ((ti + 1) * NT - ((ti + 1) * ti) / 2 <= bid) ++ti;
  while (ti * NT - (ti * (ti - 1)) / 2 > bid) --ti;
  const int tj = ti + (bid - (ti * NT - (ti * (ti - 1)) / 2));

  const int rowBase = ti * BM;
  const int colBase = tj * BM;
  const bool diag = (ti == tj);

  const char* xbb = (const char*)xb;
  const char* gA = xbb + (size_t)rowBase * 2048;
  const char* gB = xbb + (size_t)colBase * 2048;
  char* L0 = lds;
  char* L1 = lds + 65536;

  f32x4  acc[8][4] = {};
  bf16x8 aF[4][2];
  bf16x8 bF[2][2];

  // prologue: tile 0 complete (8 loads) + tile 1's A-sub0,B-sub0 (4 loads, stay in flight)
  stage_subA(L0,         gA, 0, 0, tid);
  stage_subA(L0 + 16384, gA, 1, 0, tid);
  stage_subB(L0 + 32768, gB, 0, 0, tid);
  stage_subB(L0 + 49152, gB, 1, 0, tid);
  stage_subA(L1,         gA, 0, 1, tid);
  stage_subB(L1 + 32768, gB, 0, 1, tid);
  vmwait<4>();
  barf();

#pragma unroll 1
  for (int t2 = 0; t2 < 14; t2 += 2) {
    ktile<true, true, 4>(t2,     L0, L1, gA, gB, tid, lane, wr, wc, aF, bF, acc);
    ktile<true, true, 4>(t2 + 1, L1, L0, gA, gB, tid, lane, wr, wc, aF, bF, acc);
  }
  // t=14: stage only tile-15 subs (p0/p1); drain all before t=15. t=15: nothing.
  ktile<true,  false, 0>(14, L0, L1, gA, gB, tid, lane, wr, wc, aF, bF, acc);
  ktile<false, false, -1>(15, L1, L0, gA, gB, tid, lane, wr, wc, aF, bF, acc);

  // ---- epilogue: per-row / per-col max with diagonal mask ----
  __syncthreads();
  unsigned* smaxr = (unsigned*)lds;           // [256]
  unsigned* smaxc = (unsigned*)(lds + 1024);  // [256]
  if (tid < 256) { smaxr[tid] = 0u; smaxc[tid] = 0u; }
  __syncthreads();

#pragma unroll
  for (int m = 0; m < 8; ++m) {
#pragma unroll
    for (int rr = 0; rr < 4; ++rr) {
      const int lrow = wr * 128 + m * 16 + lg * 4 + rr;  // C/D: row=(lane>>4)*4+reg
      const int grow = rowBase + lrow;
      float mx = -2.0f;
#pragma unroll
      for (int n = 0; n < 4; ++n) {
        float v = acc[m][n][rr];
        const int gcol = colBase + wc * 64 + n * 16 + lr;  // C/D: col=lane&15
        if (grow == gcol) v = -2.0f;                        // mask self-similarity
        mx = fmaxf(mx, v);
      }
#pragma unroll
      for (int off = 1; off < 16; off <<= 1) mx = fmaxf(mx, __shfl_xor(mx, off));
      if (lr == 0) atomicMax(&smaxr[lrow], encf(mx));
    }
  }
  if (!diag) {  // symmetric fold: col j's max over this block's rows
#pragma unroll
    for (int n = 0; n < 4; ++n) {
      const int lcol = wc * 64 + n * 16 + lr;
      float mx = -2.0f;
#pragma unroll
      for (int m = 0; m < 8; ++m)
#pragma unroll
        for (int rr = 0; rr < 4; ++rr) mx = fmaxf(mx, acc[m][n][rr]);
      mx = fmaxf(mx, __shfl_xor(mx, 16));
      mx = fmaxf(mx, __shfl_xor(mx, 32));
      if (lg == 0) atomicMax(&smaxc[lcol], encf(mx));
    }
  }
  __syncthreads();
  if (tid < 256) {
    atomicMax(&maxenc[rowBase + tid], smaxr[tid]);
    if (!diag) atomicMax(&maxenc[colBase + tid], smaxc[tid]);
  }
}

// ---------------- Kernel C: loss reduction ----------------
extern "C" __global__ __launch_bounds__(256)
void koleo_loss(const unsigned* __restrict__ maxenc, float* __restrict__ out) {
  const int tid = threadIdx.x;
  float sum = 0.0f;
  for (int i = tid; i < NROWS; i += 256) {
    const unsigned u    = maxenc[i];
    const unsigned bits = (u & 0x80000000u) ? (u & 0x7FFFFFFFu) : ~u;
    const float m = __uint_as_float(bits);
    const float d = sqrtf(fmaxf(2.0f - 2.0f * m, 0.0f)) + EPSF;  // ||x_i - x_nn|| + eps
    sum += logf(d + EPSF);
  }
#pragma unroll
  for (int off = 32; off > 0; off >>= 1) sum += __shfl_down(sum, off);
  __shared__ float wsum[4];
  if ((tid & 63) == 0) wsum[tid >> 6] = sum;
  __syncthreads();
  if (tid == 0) out[0] = -(wsum[0] + wsum[1] + wsum[2] + wsum[3]) / (float)NROWS;
}

extern "C" void kernel_launch(void* const* d_in, const int* in_sizes, int n_in,
                              void* d_out, int out_size, void* d_ws, size_t ws_size,
                              hipStream_t stream) {
  const float* in = (const float*)d_in[0];
  unsigned short* xb = (unsigned short*)d_ws;                                  // 16 MB bf16 x
  unsigned* maxenc   = (unsigned*)((char*)d_ws + (size_t)NROWS * DIM * 2);     // 32 KB
  float* out = (float*)d_out;

  hipLaunchKernelGGL(koleo_norm,    dim3(NROWS), dim3(256), 0, stream, in, xb, maxenc);
  hipLaunchKernelGGL(koleo_grammax, dim3(NBLK),  dim3(512), 0, stream, xb, maxenc);
  hipLaunchKernelGGL(koleo_loss,    dim3(1),     dim3(256), 0, stream, maxenc, out);
}

// Round 9
// 123.013 us; speedup vs baseline: 1.0830x; 1.0405x over previous
//
#include <hip/hip_runtime.h>

#define NROWS 8192
#define DIM   1024
#define EPSF  1e-8f

typedef __attribute__((ext_vector_type(4))) float f32x4;

typedef __attribute__((address_space(1))) void g_void;
typedef __attribute__((address_space(3))) void l_void;

__device__ __forceinline__ void async_copy16(void* lds, const void* g) {
  __builtin_amdgcn_global_load_lds((g_void*)const_cast<void*>(g), (l_void*)lds, 16, 0, 0);
}

__device__ __forceinline__ unsigned encf(float f) {
  const unsigned bits = __float_as_uint(f);
  return (bits & 0x80000000u) ? ~bits : (bits | 0x80000000u);
}

template<int N> __device__ __forceinline__ void vmwait() {
  if constexpr (N == 4)      asm volatile("s_waitcnt vmcnt(4)" ::: "memory");
  else                       asm volatile("s_waitcnt vmcnt(0)" ::: "memory");
}
__device__ __forceinline__ void barf() {
  __builtin_amdgcn_s_barrier();
  asm volatile("" ::: "memory");
}

// ---------------- Kernel A: row L2-normalize, quantize to fp8 e4m3, init maxenc ----------------
extern "C" __global__ __launch_bounds__(256)
void koleo_norm(const float* __restrict__ in, int* __restrict__ xq,
                unsigned* __restrict__ maxenc) {
  const int row = blockIdx.x;
  const int tid = threadIdx.x;
  const float4 v = reinterpret_cast<const float4*>(in + (size_t)row * DIM)[tid];
  float ss = v.x * v.x + v.y * v.y + v.z * v.z + v.w * v.w;
#pragma unroll
  for (int off = 32; off > 0; off >>= 1) ss += __shfl_down(ss, off);
  __shared__ float wsum[4];
  if ((tid & 63) == 0) wsum[tid >> 6] = ss;
  __syncthreads();
  const float total = wsum[0] + wsum[1] + wsum[2] + wsum[3];
  const float scale = 1.0f / (sqrtf(total) + EPSF);
  // pack 4 e4m3 bytes (v_cvt_pk_fp8_f32, RNE); |x|<=1 << 448 so no overflow
  int p = __builtin_amdgcn_cvt_pk_fp8_f32(v.x * scale, v.y * scale, 0, false);
  p = __builtin_amdgcn_cvt_pk_fp8_f32(v.z * scale, v.w * scale, p, true);
  xq[row * 256 + tid] = p;
  if (row < NROWS / 256) maxenc[row * 256 + tid] = 0u;  // enc(any real dot) > 0
}

// -------- Kernel B: upper-triangle Gram-max, 256x256, fp8, K-tile=128, 4-phase pipeline --------
// Byte-identical staging/swizzle/wait structure to the validated bf16 R8 kernel;
// only the payload (fp8, row stride 1024B) and MFMA innards change.
#define BM  256
#define NT  (NROWS / BM)            // 32 tiles per dim
#define NBLK (NT * (NT + 1) / 2)    // 528 upper-triangle blocks
#define NKT 8                       // 8 K-tiles of 128 fp8 elems (128 B)

// LDS buffer (64 KB): [A-sub0 | A-sub1 | B-sub0 | B-sub1], 16 KB each.
// A-sub s = wave-local rows [s*64, s*64+64) of both wr halves; read in phases {2s, 2s+1}
// B-sub s = wave-local cols [s*32, s*32+32) of all wc; read in phases {s, s+2}
// Chunk = 128 rows x 128 B, XOR-swizzled source, linear gload_lds dest (R5-proven).
__device__ __forceinline__ void stage_subA(char* dst, const char* gbase, int sub, int kt, int tid) {
#pragma unroll
  for (int l = 0; l < 2; ++l) {
    const int o  = l * 8192 + tid * 16;
    const int so = o ^ (((o >> 7) & 7) << 4);
    const int i  = so >> 7;                                  // chunk row 0..127
    const int r  = sub * 64 + (i & 63) + ((i & 64) << 1);    // global row in tile
    async_copy16(dst + o, gbase + (size_t)r * 1024 + kt * 128 + (so & 127));
  }
}
__device__ __forceinline__ void stage_subB(char* dst, const char* gbase, int sub, int kt, int tid) {
#pragma unroll
  for (int l = 0; l < 2; ++l) {
    const int o  = l * 8192 + tid * 16;
    const int so = o ^ (((o >> 7) & 7) << 4);
    const int j  = so >> 7;
    const int c  = sub * 32 + (j & 31) + ((j >> 5) << 6);    // global col in tile
    async_copy16(dst + o, gbase + (size_t)c * 1024 + kt * 128 + (so & 127));
  }
}

// fp8 16x16x32 fragment: lane (lr,lg) holds 8 contiguous K bytes at slice*32 + lg*8.
// ds_read_b64, XOR'd by row&7 like all prior rounds (2 lanes/bank = free, m136).
#define READ_A(MH)                                                                    \
  {                                                                                   \
    _Pragma("unroll")                                                                 \
    for (int mm = 0; mm < 4; ++mm)                                                    \
      _Pragma("unroll")                                                               \
      for (int s = 0; s < 4; ++s)                                                     \
        aS[mm][s] = *(const long*)(Lc + (MH) * 16384 +                                \
            ((((mm * 16 + lr) + wr * 64) * 128 + s * 32 + lg * 8) ^ xr));             \
  }
#define READ_B(NH)                                                                    \
  {                                                                                   \
    _Pragma("unroll")                                                                 \
    for (int nn = 0; nn < 2; ++nn)                                                    \
      _Pragma("unroll")                                                               \
      for (int s = 0; s < 4; ++s)                                                     \
        bS[nn][s] = *(const long*)(Lc + 32768 + (NH) * 16384 +                        \
            ((((nn * 16 + lr) + wc * 32) * 128 + s * 32 + lg * 8) ^ xr));             \
  }
#define MFMAQ(MH, NH)                                                                 \
  {                                                                                   \
    _Pragma("unroll")                                                                 \
    for (int s = 0; s < 4; ++s)                                                       \
      _Pragma("unroll")                                                               \
      for (int mm = 0; mm < 4; ++mm)                                                  \
        _Pragma("unroll")                                                             \
        for (int nn = 0; nn < 2; ++nn)                                                \
          acc[(MH)*4 + mm][(NH)*2 + nn] = __builtin_amdgcn_mfma_f32_16x16x32_fp8_fp8( \
              aS[mm][s], bS[nn][s], acc[(MH)*4 + mm][(NH)*2 + nn], 0, 0, 0);          \
  }

// Stage schedule per tile t (reads Lc): p0: A-sub1(t+1)->Ln  p1: B-sub1(t+1)->Ln
// p2: A-sub0(t+2)->Lc  p3: B-sub0(t+2)->Lc. Single counted vmcnt(4) at p3
// (tile t+1 complete, t+2's 4 newest loads stay in flight). Same WAR/wait proofs as R8.
template<bool S01, bool S23, int VB>
__device__ __forceinline__ void ktile(int t, char* Lc, char* Ln,
    const char* gA, const char* gB, int tid, int lane, int wr, int wc,
    long (&aS)[4][4], long (&bS)[2][4], f32x4 (&acc)[8][4]) {
  const int lr = lane & 15, lg = lane >> 4;
  const int xr = (lane & 7) << 4;
  // ---- p0: quadrant (0,0) ----
  READ_A(0); READ_B(0);
  if constexpr (S01) stage_subA(Ln + 16384, gA, 1, t + 1, tid);
  barf();
  __builtin_amdgcn_s_setprio(1); MFMAQ(0, 0); __builtin_amdgcn_s_setprio(0);
  barf();
  // ---- p1: quadrant (0,1), aS reused ----
  READ_B(1);
  if constexpr (S01) stage_subB(Ln + 49152, gB, 1, t + 1, tid);
  barf();
  __builtin_amdgcn_s_setprio(1); MFMAQ(0, 1); __builtin_amdgcn_s_setprio(0);
  barf();
  // ---- p2: quadrant (1,0) ----
  READ_A(1); READ_B(0);
  if constexpr (S23) stage_subA(Lc, gA, 0, t + 2, tid);
  barf();
  __builtin_amdgcn_s_setprio(1); MFMAQ(1, 0); __builtin_amdgcn_s_setprio(0);
  barf();
  // ---- p3: quadrant (1,1); the one counted wait per K-tile ----
  READ_B(1);
  if constexpr (S23) stage_subB(Lc + 32768, gB, 0, t + 2, tid);
  if constexpr (VB >= 0) vmwait<VB>();
  barf();
  __builtin_amdgcn_s_setprio(1); MFMAQ(1, 1); __builtin_amdgcn_s_setprio(0);
  barf();
}

extern "C" __global__ __launch_bounds__(512)
void koleo_grammax(const char* __restrict__ xq, unsigned* __restrict__ maxenc) {
  __shared__ char lds[131072];   // 2 dbuf x 64KB

  const int tid  = threadIdx.x;
  const int lane = tid & 63;
  const int wid  = tid >> 6;
  const int wr   = wid >> 2;     // 0..1: rows wr*128..+127
  const int wc   = wid & 3;      // 0..3: cols wc*64..+63
  const int lr   = lane & 15;
  const int lg   = lane >> 4;

  // XCD-aware bijective swizzle (528 % 8 == 0)
  const int bid = (blockIdx.x % 8) * (NBLK / 8) + blockIdx.x / 8;
  // upper-triangle decode (ti <= tj)
  int ti = (int)((2.0f * NT + 1.0f -
                  sqrtf((float)((2 * NT + 1) * (2 * NT + 1) - 8 * bid))) * 0.5f);
  while ((ti + 1) * NT - ((ti + 1) * ti) / 2 <= bid) ++ti;
  while (ti * NT - (ti * (ti - 1)) / 2 > bid) --ti;
  const int tj = ti + (bid - (ti * NT - (ti * (ti - 1)) / 2));

  const int rowBase = ti * BM;
  const int colBase = tj * BM;
  const bool diag = (ti == tj);

  const char* gA = xq + (size_t)rowBase * 1024;
  const char* gB = xq + (size_t)colBase * 1024;
  char* L0 = lds;
  char* L1 = lds + 65536;

  f32x4 acc[8][4] = {};
  long  aS[4][4];
  long  bS[2][4];

  // prologue: tile 0 complete + tile 1's A-sub0,B-sub0 (4 loads stay in flight)
  stage_subA(L0,         gA, 0, 0, tid);
  stage_subA(L0 + 16384, gA, 1, 0, tid);
  stage_subB(L0 + 32768, gB, 0, 0, tid);
  stage_subB(L0 + 49152, gB, 1, 0, tid);
  stage_subA(L1,         gA, 0, 1, tid);
  stage_subB(L1 + 32768, gB, 0, 1, tid);
  vmwait<4>();
  barf();

#pragma unroll 1
  for (int t2 = 0; t2 < 6; t2 += 2) {
    ktile<true, true, 4>(t2,     L0, L1, gA, gB, tid, lane, wr, wc, aS, bS, acc);
    ktile<true, true, 4>(t2 + 1, L1, L0, gA, gB, tid, lane, wr, wc, aS, bS, acc);
  }
  // t=6: stage only tile-7 sub1s; drain. t=7: nothing.
  ktile<true,  false, 0>(6, L0, L1, gA, gB, tid, lane, wr, wc, aS, bS, acc);
  ktile<false, false, -1>(7, L1, L0, gA, gB, tid, lane, wr, wc, aS, bS, acc);

  // ---- epilogue: per-row / per-col max with diagonal mask (C/D layout dtype-independent) ----
  __syncthreads();
  unsigned* smaxr = (unsigned*)lds;           // [256]
  unsigned* smaxc = (unsigned*)(lds + 1024);  // [256]
  if (tid < 256) { smaxr[tid] = 0u; smaxc[tid] = 0u; }
  __syncthreads();

#pragma unroll
  for (int m = 0; m < 8; ++m) {
#pragma unroll
    for (int rr = 0; rr < 4; ++rr) {
      const int lrow = wr * 128 + m * 16 + lg * 4 + rr;  // C/D: row=(lane>>4)*4+reg
      const int grow = rowBase + lrow;
      float mx = -2.0f;
#pragma unroll
      for (int n = 0; n < 4; ++n) {
        float v = acc[m][n][rr];
        const int gcol = colBase + wc * 64 + n * 16 + lr;  // C/D: col=lane&15
        if (grow == gcol) v = -2.0f;                        // mask self-similarity
        mx = fmaxf(mx, v);
      }
#pragma unroll
      for (int off = 1; off < 16; off <<= 1) mx = fmaxf(mx, __shfl_xor(mx, off));
      if (lr == 0) atomicMax(&smaxr[lrow], encf(mx));
    }
  }
  if (!diag) {  // symmetric fold: col j's max over this block's rows
#pragma unroll
    for (int n = 0; n < 4; ++n) {
      const int lcol = wc * 64 + n * 16 + lr;
      float mx = -2.0f;
#pragma unroll
      for (int m = 0; m < 8; ++m)
#pragma unroll
        for (int rr = 0; rr < 4; ++rr) mx = fmaxf(mx, acc[m][n][rr]);
      mx = fmaxf(mx, __shfl_xor(mx, 16));
      mx = fmaxf(mx, __shfl_xor(mx, 32));
      if (lg == 0) atomicMax(&smaxc[lcol], encf(mx));
    }
  }
  __syncthreads();
  if (tid < 256) {
    atomicMax(&maxenc[rowBase + tid], smaxr[tid]);
    if (!diag) atomicMax(&maxenc[colBase + tid], smaxc[tid]);
  }
}

// ---------------- Kernel C: loss reduction ----------------
extern "C" __global__ __launch_bounds__(256)
void koleo_loss(const unsigned* __restrict__ maxenc, float* __restrict__ out) {
  const int tid = threadIdx.x;
  float sum = 0.0f;
  for (int i = tid; i < NROWS; i += 256) {
    const unsigned u    = maxenc[i];
    const unsigned bits = (u & 0x80000000u) ? (u & 0x7FFFFFFFu) : ~u;
    const float m = __uint_as_float(bits);
    const float d = sqrtf(fmaxf(2.0f - 2.0f * m, 0.0f)) + EPSF;  // ||x_i - x_nn|| + eps
    sum += logf(d + EPSF);
  }
#pragma unroll
  for (int off = 32; off > 0; off >>= 1) sum += __shfl_down(sum, off);
  __shared__ float wsum[4];
  if ((tid & 63) == 0) wsum[tid >> 6] = sum;
  __syncthreads();
  if (tid == 0) out[0] = -(wsum[0] + wsum[1] + wsum[2] + wsum[3]) / (float)NROWS;
}

extern "C" void kernel_launch(void* const* d_in, const int* in_sizes, int n_in,
                              void* d_out, int out_size, void* d_ws, size_t ws_size,
                              hipStream_t stream) {
  const float* in = (const float*)d_in[0];
  char* xq         = (char*)d_ws;                                        // 8 MB fp8 x
  unsigned* maxenc = (unsigned*)((char*)d_ws + (size_t)NROWS * DIM);     // 32 KB
  float* out = (float*)d_out;

  hipLaunchKernelGGL(koleo_norm,    dim3(NROWS), dim3(256), 0, stream, in, (int*)xq, maxenc);
  hipLaunchKernelGGL(koleo_grammax, dim3(NBLK),  dim3(512), 0, stream, xq, maxenc);
  hipLaunchKernelGGL(koleo_loss,    dim3(1),     dim3(256), 0, stream, maxenc, out);
}

// Round 11
// 83.136 us; speedup vs baseline: 1.6024x; 1.4797x over previous
//
#include <hip/hip_runtime.h>

#define NROWS 8192
#define DIM   1024
#define EPSF  1e-8f

typedef __attribute__((ext_vector_type(4))) float f32x4;

typedef __attribute__((address_space(1))) void g_void;
typedef __attribute__((address_space(3))) void l_void;

__device__ __forceinline__ void async_copy16(void* lds, const void* g) {
  __builtin_amdgcn_global_load_lds((g_void*)const_cast<void*>(g), (l_void*)lds, 16, 0, 0);
}

__device__ __forceinline__ unsigned encf(float f) {
  const unsigned bits = __float_as_uint(f);
  return (bits & 0x80000000u) ? ~bits : (bits | 0x80000000u);
}

template<int N> __device__ __forceinline__ void vmwait() {
  if constexpr (N == 8)      asm volatile("s_waitcnt vmcnt(8)" ::: "memory");
  else                       asm volatile("s_waitcnt vmcnt(0)" ::: "memory");
}
__device__ __forceinline__ void barf() {
  __builtin_amdgcn_s_barrier();
  asm volatile("" ::: "memory");
}

// ---------------- Kernel A: row L2-normalize, quantize to fp8 e4m3, init maxenc ----------------
// (identical to R9 — proven absmax 0.0)
extern "C" __global__ __launch_bounds__(256)
void koleo_norm(const float* __restrict__ in, int* __restrict__ xq,
                unsigned* __restrict__ maxenc) {
  const int row = blockIdx.x;
  const int tid = threadIdx.x;
  const float4 v = reinterpret_cast<const float4*>(in + (size_t)row * DIM)[tid];
  float ss = v.x * v.x + v.y * v.y + v.z * v.z + v.w * v.w;
#pragma unroll
  for (int off = 32; off > 0; off >>= 1) ss += __shfl_down(ss, off);
  __shared__ float wsum[4];
  if ((tid & 63) == 0) wsum[tid >> 6] = ss;
  __syncthreads();
  const float total = wsum[0] + wsum[1] + wsum[2] + wsum[3];
  const float scale = 1.0f / (sqrtf(total) + EPSF);
  int p = __builtin_amdgcn_cvt_pk_fp8_f32(v.x * scale, v.y * scale, 0, false);
  p = __builtin_amdgcn_cvt_pk_fp8_f32(v.z * scale, v.w * scale, p, true);
  xq[row * 256 + tid] = p;
  if (row < NROWS / 256) maxenc[row * 256 + tid] = 0u;  // enc(any real dot) > 0
}

// -------- Kernel B: upper-triangle Gram-max, 128x128 fp8 tiles, 2 blocks/CU, 2-phase --------
#define BM 128
#define NT  (NROWS / BM)            // 64 tiles per dim
#define NBLK (NT * (NT + 1) / 2)    // 2080 upper-triangle blocks
#define NKT 8                       // 8 K-tiles of 128 fp8 bytes

// stage one 16KB chunk = 128 rows x 128B (one operand, one K-tile), 256 threads.
// XOR-swizzled SOURCE, linear gload_lds dest (R5/R9-proven):
// LDS[row][c] = global[row][c ^ ((row&7)<<4)]
__device__ __forceinline__ void stage_chunk(char* dst, const char* gbase, int kt, int tid) {
#pragma unroll
  for (int l = 0; l < 4; ++l) {
    const int o  = l * 4096 + tid * 16;
    const int so = o ^ (((o >> 7) & 7) << 4);
    async_copy16(dst + o, gbase + (size_t)(so >> 7) * 1024 + kt * 128 + (so & 127));
  }
}

// fp8 16x16x32 fragment reads (R9-proven): lane (lr,lg) kstep s -> 8 bytes at
// row*128 + s*32 + lg*8, XOR'd by (row&7)<<4 == xr (involution cancels the stage swizzle).
#define READ_AB(S0)                                                                   \
  {                                                                                   \
    _Pragma("unroll")                                                                 \
    for (int mm = 0; mm < 4; ++mm)                                                    \
      _Pragma("unroll")                                                               \
      for (int s = 0; s < 2; ++s)                                                     \
        aS[mm][s] = *(const long*)(Lc +                                               \
            (((wr * 64 + mm * 16 + lr) * 128 + ((S0) + s) * 32 + lg * 8) ^ xr));      \
    _Pragma("unroll")                                                                 \
    for (int nn = 0; nn < 4; ++nn)                                                    \
      _Pragma("unroll")                                                               \
      for (int s = 0; s < 2; ++s)                                                     \
        bS[nn][s] = *(const long*)(Lc + 16384 +                                       \
            (((wc * 64 + nn * 16 + lr) * 128 + ((S0) + s) * 32 + lg * 8) ^ xr));      \
  }
#define MFMA2()                                                                       \
  {                                                                                   \
    _Pragma("unroll")                                                                 \
    for (int s = 0; s < 2; ++s)                                                       \
      _Pragma("unroll")                                                               \
      for (int mm = 0; mm < 4; ++mm)                                                  \
        _Pragma("unroll")                                                             \
        for (int nn = 0; nn < 4; ++nn)                                                \
          acc[mm][nn] = __builtin_amdgcn_mfma_f32_16x16x32_fp8_fp8(                   \
              aS[mm][s], bS[nn][s], acc[mm][nn], 0, 0, 0);                            \
  }

// Per K-tile t (buffer Lc): p0 {read ks0-1, MFMA}; p1 {read ks2-3, BAR (all tile-t
// reads issued/drained before stores land), stage tile t+2 -> Lc (8 loads),
// vmcnt(8) = tile t+1 complete with t+2's 8 loads still in flight, BAR, MFMA}.
// Same wait arithmetic as validated R7/R9.
template<bool ST, int V>
__device__ __forceinline__ void ktile(int t, char* Lc,
    const char* gA, const char* gB, int tid, int lane, int wr, int wc,
    long (&aS)[4][2], long (&bS)[4][2], f32x4 (&acc)[4][4]) {
  const int lr = lane & 15, lg = lane >> 4;
  const int xr = (lane & 7) << 4;
  // ---- p0: ksteps 0-1 ----
  READ_AB(0);
  __builtin_amdgcn_s_setprio(1); MFMA2(); __builtin_amdgcn_s_setprio(0);
  // ---- p1: ksteps 2-3 ----
  READ_AB(2);
  barf();                                   // all waves' tile-t reads precede stages
  if constexpr (ST) {
    stage_chunk(Lc,         gA, t + 2, tid);
    stage_chunk(Lc + 16384, gB, t + 2, tid);
  }
  if constexpr (V >= 0) vmwait<V>();        // tile t+1 data complete
  barf();                                   // fence before next tile's reads
  __builtin_amdgcn_s_setprio(1); MFMA2(); __builtin_amdgcn_s_setprio(0);
}

extern "C" __global__ __launch_bounds__(256)
void koleo_grammax(const char* __restrict__ xq, unsigned* __restrict__ maxenc) {
  __shared__ char lds[65536];   // 2 dbuf x (A 16KB + B 16KB) -> 2 blocks/CU

  const int tid  = threadIdx.x;
  const int lane = tid & 63;
  const int wid  = tid >> 6;
  const int wr   = wid >> 1;     // 0..1: rows wr*64..+63
  const int wc   = wid & 1;      // 0..1: cols wc*64..+63
  const int lr   = lane & 15;
  const int lg   = lane >> 4;

  // XCD-aware bijective swizzle (2080 % 8 == 0)
  const int bid = (blockIdx.x % 8) * (NBLK / 8) + blockIdx.x / 8;
  // upper-triangle decode (ti <= tj), NT=64 (R1-proven)
  int ti = (int)((2.0f * NT + 1.0f -
                  sqrtf((float)((2 * NT + 1) * (2 * NT + 1) - 8 * bid))) * 0.5f);
  while ((ti + 1) * NT - ((ti + 1) * ti) / 2 <= bid) ++ti;
  while (ti * NT - (ti * (ti - 1)) / 2 > bid) --ti;
  const int tj = ti + (bid - (ti * NT - (ti * (ti - 1)) / 2));

  const int rowBase = ti * BM;
  const int colBase = tj * BM;
  const bool diag = (ti == tj);

  const char* gA = xq + (size_t)rowBase * 1024;
  const char* gB = xq + (size_t)colBase * 1024;
  char* L0 = lds;
  char* L1 = lds + 32768;

  f32x4 acc[4][4] = {};
  long  aS[4][2];
  long  bS[4][2];

  // prologue: tile 0 -> L0 (8 loads), tile 1 -> L1 (8 loads)
  stage_chunk(L0,         gA, 0, tid);
  stage_chunk(L0 + 16384, gB, 0, tid);
  stage_chunk(L1,         gA, 1, tid);
  stage_chunk(L1 + 16384, gB, 1, tid);
  vmwait<8>();   // tile 0 complete; tile 1's 8 loads in flight
  barf();

#pragma unroll 1
  for (int t2 = 0; t2 < 6; t2 += 2) {
    ktile<true, 8>(t2,     L0, gA, gB, tid, lane, wr, wc, aS, bS, acc);
    ktile<true, 8>(t2 + 1, L1, gA, gB, tid, lane, wr, wc, aS, bS, acc);
  }
  ktile<false, 0>(6, L0, gA, gB, tid, lane, wr, wc, aS, bS, acc);   // drain tile-7 loads
  ktile<false, -1>(7, L1, gA, gB, tid, lane, wr, wc, aS, bS, acc);

  // ---- epilogue: per-row / per-col max with diagonal mask (16x16 C/D layout) ----
  __syncthreads();
  unsigned* smaxr = (unsigned*)lds;           // [128]
  unsigned* smaxc = (unsigned*)(lds + 512);   // [128]
  if (tid < 128) { smaxr[tid] = 0u; smaxc[tid] = 0u; }
  __syncthreads();

#pragma unroll
  for (int m = 0; m < 4; ++m) {
#pragma unroll
    for (int rr = 0; rr < 4; ++rr) {
      const int lrow = wr * 64 + m * 16 + lg * 4 + rr;  // C/D: row=(lane>>4)*4+reg
      const int grow = rowBase + lrow;
      float mx = -2.0f;
#pragma unroll
      for (int n = 0; n < 4; ++n) {
        float v = acc[m][n][rr];
        const int gcol = colBase + wc * 64 + n * 16 + lr;  // C/D: col=lane&15
        if (grow == gcol) v = -2.0f;                        // mask self-similarity
        mx = fmaxf(mx, v);
      }
#pragma unroll
      for (int off = 1; off < 16; off <<= 1) mx = fmaxf(mx, __shfl_xor(mx, off));
      if (lr == 0) atomicMax(&smaxr[lrow], encf(mx));
    }
  }
  if (!diag) {  // symmetric fold: col j's max over this block's rows
#pragma unroll
    for (int n = 0; n < 4; ++n) {
      const int lcol = wc * 64 + n * 16 + lr;
      float mx = -2.0f;
#pragma unroll
      for (int m = 0; m < 4; ++m)
#pragma unroll
        for (int rr = 0; rr < 4; ++rr) mx = fmaxf(mx, acc[m][n][rr]);
      mx = fmaxf(mx, __shfl_xor(mx, 16));
      mx = fmaxf(mx, __shfl_xor(mx, 32));
      if (lg == 0) atomicMax(&smaxc[lcol], encf(mx));
    }
  }
  __syncthreads();
  if (tid < 128) {
    atomicMax(&maxenc[rowBase + tid], smaxr[tid]);
    if (!diag) atomicMax(&maxenc[colBase + tid], smaxc[tid]);
  }
}

// ---------------- Kernel C: loss reduction ----------------
extern "C" __global__ __launch_bounds__(1024)
void koleo_loss(const unsigned* __restrict__ maxenc, float* __restrict__ out) {
  const int tid = threadIdx.x;
  float sum = 0.0f;
#pragma unroll
  for (int i = tid; i < NROWS; i += 1024) {
    const unsigned u    = maxenc[i];
    const unsigned bits = (u & 0x80000000u) ? (u & 0x7FFFFFFFu) : ~u;
    const float m = __uint_as_float(bits);
    const float d = sqrtf(fmaxf(2.0f - 2.0f * m, 0.0f)) + EPSF;  // ||x_i - x_nn|| + eps
    sum += logf(d + EPSF);
  }
#pragma unroll
  for (int off = 32; off > 0; off >>= 1) sum += __shfl_down(sum, off);
  __shared__ float wsum[16];
  if ((tid & 63) == 0) wsum[tid >> 6] = sum;
  __syncthreads();
  if (tid == 0) {
    float t = 0.0f;
#pragma unroll
    for (int w = 0; w < 16; ++w) t += wsum[w];
    out[0] = -t / (float)NROWS;
  }
}

extern "C" void kernel_launch(void* const* d_in, const int* in_sizes, int n_in,
                              void* d_out, int out_size, void* d_ws, size_t ws_size,
                              hipStream_t stream) {
  const float* in = (const float*)d_in[0];
  char* xq         = (char*)d_ws;                                        // 8 MB fp8 x
  unsigned* maxenc = (unsigned*)((char*)d_ws + (size_t)NROWS * DIM);     // 32 KB
  float* out = (float*)d_out;

  hipLaunchKernelGGL(koleo_norm,    dim3(NROWS), dim3(256),  0, stream, in, (int*)xq, maxenc);
  hipLaunchKernelGGL(koleo_grammax, dim3(NBLK),  dim3(256),  0, stream, xq, maxenc);
  hipLaunchKernelGGL(koleo_loss,    dim3(1),     dim3(1024), 0, stream, maxenc, out);
}